// Round 15
// baseline (300.784 us; speedup 1.0000x reference)
//
#include <hip/hip_runtime.h>
#include <hip/hip_bf16.h>

typedef __bf16 bf16x8 __attribute__((ext_vector_type(8)));
typedef float f32x4 __attribute__((ext_vector_type(4)));
typedef __attribute__((address_space(3))) void lds_void_t;
typedef __attribute__((address_space(1))) void gbl_void_t;

#define LRELU(x) ((x) >= 0.f ? (x) : 0.2f * (x))

__device__ __forceinline__ void gload16(void* lds_uniform, const void* gsrc) {
    __builtin_amdgcn_global_load_lds((const gbl_void_t*)gsrc, (lds_void_t*)lds_uniform,
                                     16, 0, 0);
}

__device__ __forceinline__ unsigned short f2u(float f) {
    __hip_bfloat16 h = __float2bfloat16(f);
    return reinterpret_cast<unsigned short&>(h);
}

// ---------------- fused f32 -> bf16 convert (weights only) -----------------
__global__ void cvt_w(const float* __restrict__ a, __hip_bfloat16* __restrict__ oa, int na,
                      const float* __restrict__ b, __hip_bfloat16* __restrict__ ob, int nb,
                      const float* __restrict__ c, __hip_bfloat16* __restrict__ oc, int nc) {
    const int stride = gridDim.x * blockDim.x;
    const int total = na + nb + nc;
    for (int i = blockIdx.x * blockDim.x + threadIdx.x; i < total; i += stride) {
        const float* s; __hip_bfloat16* o; int j = i;
        if (j < na) { s = a; o = oa; }
        else {
            j -= na;
            if (j < nb) { s = b; o = ob; }
            else { j -= nb; s = c; o = oc; }
        }
        float4 v = reinterpret_cast<const float4*>(s)[j];
        ushort4 u;
        u.x = f2u(v.x); u.y = f2u(v.y); u.z = f2u(v.z); u.w = f2u(v.w);
        reinterpret_cast<ushort4*>(o)[j] = u;
    }
}

// ======================= 256x256 8-phase GEMM (R8 + T14 A-path) ============
// 8 waves (2M x 4N), per-wave C = 128x64 (acc[8][4] f32x4). BK=64, 2 K-tiles
// per iteration. LDS = 2 bufs x 4 regions (A0,A1,B0,B1) x 8192 elems = 128KB.
// Chunk-XOR swizzle: chunk c of row r at position c^(r&7); linear dest +
// pre-swizzled global source; same XOR on ds_read.
// ASRC=0: A staged via global_load_lds from bf16 A (R8-proven).
// ASRC=1: A staged from f32 Af with T14 issue-early/write-late (4-phase gap):
//   P1/P2: LD rE = f32 A(U+2), WR rO -> buf1 (loaded 4 phases ago)
//   P5/P6: LD rO = f32 A(U+3), WR rE -> buf0
//   Compiler auto-inserts COUNTED vmcnt before each cvt (data dep); loads
//   pinned in their phase window by the existing sched_barrier(0)s.
// Ledger: B-RAW publishes at P4/P8: newer-than-drained = 2+2 B-gloads +
//   (ASRC==1 ? 8 in-flight f32 loads : 0) -> vmcnt(4) / vmcnt(12). Last iter
//   vmcnt(0). A-RAW (ASRC=1): WR at Pk drained by Pk's PH_MID lgkm0 (own
//   wave) + Pk's END barrier (block-wide), first read >=3 barriers later
//   (P1/P2 write -> P5 read; P5/P6 write -> next-P1 read). WAR ages as R8.
// MODE 1: out = bf16(lrelu(bn(A@B^T)) + xq) ; MODE 2: out = bf16(lrelu(bn))
// ===========================================================================

#define MMQ(AF, BF, IH, JH)                                                   \
    {                                                                         \
        _Pragma("unroll") for (int r = 0; r < 4; ++r) {                       \
            _Pragma("unroll") for (int c = 0; c < 2; ++c) {                   \
                _Pragma("unroll") for (int s = 0; s < 2; ++s) {               \
                    acc[(IH) * 4 + r][(JH) * 2 + c] =                         \
                        __builtin_amdgcn_mfma_f32_16x16x32_bf16(              \
                            AF[r][s], BF[c][s],                               \
                            acc[(IH) * 4 + r][(JH) * 2 + c], 0, 0, 0);        \
                }                                                             \
            }                                                                 \
        }                                                                     \
    }

#define LDA_(AF, BUF, IH)                                                     \
    {                                                                         \
        const __hip_bfloat16* _ab = sm + (BUF) * 32768 + wm * 8192;           \
        _Pragma("unroll") for (int r = 0; r < 4; ++r) {                       \
            const int _row = (IH) * 64 + r * 16 + lr;                         \
            _Pragma("unroll") for (int s = 0; s < 2; ++s) {                   \
                AF[r][s] = *reinterpret_cast<const bf16x8*>(                  \
                    _ab + _row * 64 + (((s * 4 + kg) ^ (lr & 7)) * 8));       \
            }                                                                 \
        }                                                                     \
    }

#define LDB_(BF, BUF, JH)                                                     \
    {                                                                         \
        const __hip_bfloat16* _bb =                                           \
            sm + (BUF) * 32768 + (2 + (wn >> 1)) * 8192;                      \
        _Pragma("unroll") for (int c = 0; c < 2; ++c) {                       \
            const int _row = (wn & 1) * 64 + ((JH) * 2 + c) * 16 + lr;        \
            _Pragma("unroll") for (int s = 0; s < 2; ++s) {                   \
                BF[c][s] = *reinterpret_cast<const bf16x8*>(                  \
                    _bb + _row * 64 + (((s * 4 + kg) ^ (lr & 7)) * 8));       \
            }                                                                 \
        }                                                                     \
    }

#define PH_MID                                                                \
    __builtin_amdgcn_s_barrier();                                             \
    asm volatile("s_waitcnt lgkmcnt(0)" ::: "memory");                        \
    __builtin_amdgcn_sched_barrier(0);                                        \
    __builtin_amdgcn_s_setprio(1);

#define PH_END                                                                \
    __builtin_amdgcn_s_setprio(0);                                            \
    __builtin_amdgcn_sched_barrier(0);                                        \
    __builtin_amdgcn_s_barrier();

template <int N, int K, int MODE, int ASRC>
__global__ __launch_bounds__(512, 1)
void gemm8p(const __hip_bfloat16* __restrict__ A,
            const float* __restrict__ Af,
            const __hip_bfloat16* __restrict__ Bw,
            const float* __restrict__ xq,
            __hip_bfloat16* __restrict__ out,
            const float* __restrict__ Gg, const float* __restrict__ Gb,
            const float* __restrict__ Gm, const float* __restrict__ Gv) {
    __shared__ __hip_bfloat16 sm[65536];   // 128 KB

    // XCD-aware block swizzle (nwg % 8 == 0 by launch config); consecutive
    // orig share an A row-panel -> same XCD -> f32 A re-reads are L2-local.
    const int nwg = gridDim.x;
    const int cpx = nwg >> 3;
    const int bid = blockIdx.x;
    const int orig = (bid & 7) * cpx + (bid >> 3);
    constexpr int NCB = N / 256;
    const int row0 = (orig / NCB) * 256;
    const int col0 = (orig % NCB) * 256;

    const int tid = threadIdx.x;
    const int lane = tid & 63;
    const int wv = tid >> 6;          // 0..7
    const int wm = wv >> 2, wn = wv & 3;
    const int lr = lane & 15, kg = lane >> 4;

    // staging source: thread tid covers LDS elems 8*tid (row=tid>>3,
    // chunk pos=tid&7); source chunk = pos ^ (row&7) (pre-swizzled).
    const int schunk = (tid & 7) ^ ((tid >> 3) & 7);
    const __hip_bfloat16* srcA0 = A + (size_t)(row0 + (tid >> 3)) * K + schunk * 8;
    const float* srcAf = Af + (size_t)(row0 + (tid >> 3)) * K + schunk * 8;
    const __hip_bfloat16* srcB0 = Bw + (size_t)(col0 + (tid >> 3)) * K + schunk * 8;
    constexpr size_t H = (size_t)128 * K;   // +128 rows (second half-tile)

    auto STG = [&](int buf, int region, const __hip_bfloat16* src) {
        __hip_bfloat16* l = sm + buf * 32768 + region * 8192 + wv * 512;
        gload16(l, src);
        gload16(l + 4096, src + (size_t)64 * K);   // g=1: rows +64
    };
    // T14 A-path: issue f32 loads (4 x float4 per region) ...
    auto LD_A32 = [&](float4* r, int elemoff) {
#pragma unroll
        for (int g = 0; g < 2; ++g) {
            const float* s = srcAf + elemoff + g * (size_t)64 * K;
            r[g * 2 + 0] = *reinterpret_cast<const float4*>(s);
            r[g * 2 + 1] = *reinterpret_cast<const float4*>(s + 4);
        }
    };
    // ... and cvt + ds_write 4 phases later (same LDS layout as gload_lds)
    auto WR_A32 = [&](int buf, int region, const float4* r) {
        __hip_bfloat16* l = sm + buf * 32768 + region * 8192 + tid * 8;
#pragma unroll
        for (int g = 0; g < 2; ++g) {
            bf16x8 v;
            v[0] = (__bf16)r[g * 2].x;     v[1] = (__bf16)r[g * 2].y;
            v[2] = (__bf16)r[g * 2].z;     v[3] = (__bf16)r[g * 2].w;
            v[4] = (__bf16)r[g * 2 + 1].x; v[5] = (__bf16)r[g * 2 + 1].y;
            v[6] = (__bf16)r[g * 2 + 1].z; v[7] = (__bf16)r[g * 2 + 1].w;
            *reinterpret_cast<bf16x8*>(l + g * 4096) = v;
        }
    };

    f32x4 acc[8][4];
#pragma unroll
    for (int i = 0; i < 8; ++i)
#pragma unroll
        for (int j = 0; j < 4; ++j) acc[i][j] = (f32x4){0.f, 0.f, 0.f, 0.f};

    bf16x8 af[4][2], bfrL[2][2], bfrH[2][2];
    float4 rE0[4], rE1[4], rO0[4], rO1[4];   // loop-carried A f32 (ASRC=1)

    // ---- prologue ----
    if constexpr (ASRC == 1) {
        float4 t0[4], t1[4];
        LD_A32(t0, 0); LD_A32(t1, (int)H);            // A(tile 0)
        STG(0, 2, srcB0);          // B0(T0)
        STG(0, 3, srcB0 + H);      // B1(T0)
        STG(1, 2, srcB0 + 64);     // B0(T1)
        STG(1, 3, srcB0 + H + 64); // B1(T1)
        LD_A32(rO0, 64); LD_A32(rO1, (int)H + 64);    // A(tile 1)
        WR_A32(0, 0, t0); WR_A32(0, 1, t1);           // auto-vmcnt drains t0/t1
        asm volatile("s_waitcnt vmcnt(12)" ::: "memory");  // buf0-B landed
        asm volatile("s_waitcnt lgkmcnt(0)" ::: "memory"); // own A-writes done
    } else {
        STG(0, 0, srcA0);          // A0(T0)
        STG(0, 1, srcA0 + H);      // A1(T0)
        STG(0, 2, srcB0);          // B0(T0)
        STG(0, 3, srcB0 + H);      // B1(T0)
        STG(1, 2, srcB0 + 64);     // B0(T1)
        STG(1, 3, srcB0 + H + 64); // B1(T1)
        asm volatile("s_waitcnt vmcnt(4)" ::: "memory");   // buf0 landed
    }
    __builtin_amdgcn_s_barrier();

    constexpr int niter = K / 128;
    for (int it = 0; it < niter; ++it) {
        const int k0 = it * 128;           // tile U k-offset
        const bool pf = (it + 1 < niter);

        // ---- P1: buf0 Q(0,0) | A0(U+1)->buf1 (+ LD A0(U+2) if ASRC=1) ----
        if constexpr (ASRC == 1) {
            if (pf) LD_A32(rE0, k0 + 128);
            WR_A32(1, 0, rO0);
        } else {
            STG(1, 0, srcA0 + k0 + 64);
        }
        LDA_(af, 0, 0);
        LDB_(bfrL, 0, 0);
        PH_MID; MMQ(af, bfrL, 0, 0); PH_END;

        // ---- P2: buf0 Q(0,1) | A1(U+1)->buf1 (+ LD A1(U+2)) ----
        if constexpr (ASRC == 1) {
            if (pf) LD_A32(rE1, (int)H + k0 + 128);
            WR_A32(1, 1, rO1);
        } else {
            STG(1, 1, srcA0 + H + k0 + 64);
        }
        LDB_(bfrH, 0, 1);
        PH_MID; MMQ(af, bfrH, 0, 1); PH_END;

        // ---- P3: buf0 Q(1,1) | stage B0(U+2)->buf0 ----
        LDA_(af, 0, 1);
        if (pf) STG(0, 2, srcB0 + k0 + 128);
        PH_MID; MMQ(af, bfrH, 1, 1); PH_END;

        // ---- P4: buf0 Q(1,0) | stage B1(U+2)->buf0 | publish buf1 ----
        if (pf) {
            STG(0, 3, srcB0 + H + k0 + 128);
            if constexpr (ASRC == 1)
                asm volatile("s_waitcnt vmcnt(12)" ::: "memory");
            else
                asm volatile("s_waitcnt vmcnt(4)" ::: "memory");
        } else {
            asm volatile("s_waitcnt vmcnt(0)" ::: "memory");
        }
        PH_MID; MMQ(af, bfrL, 1, 0); PH_END;

        // ---- P5: buf1 Q(0,0) | A0(U+2)->buf0 (+ LD A0(U+3)) ----
        LDA_(af, 1, 0);
        LDB_(bfrL, 1, 0);
        if constexpr (ASRC == 1) {
            if (pf) { LD_A32(rO0, k0 + 192); WR_A32(0, 0, rE0); }
        } else {
            if (pf) STG(0, 0, srcA0 + k0 + 128);
        }
        PH_MID; MMQ(af, bfrL, 0, 0); PH_END;

        // ---- P6: buf1 Q(0,1) | A1(U+2)->buf0 (+ LD A1(U+3)) ----
        LDB_(bfrH, 1, 1);
        if constexpr (ASRC == 1) {
            if (pf) { LD_A32(rO1, (int)H + k0 + 192); WR_A32(0, 1, rE1); }
        } else {
            if (pf) STG(0, 1, srcA0 + H + k0 + 128);
        }
        PH_MID; MMQ(af, bfrH, 0, 1); PH_END;

        // ---- P7: buf1 Q(1,1) | stage B0(U+3)->buf1 ----
        LDA_(af, 1, 1);
        if (pf) STG(1, 2, srcB0 + k0 + 192);
        PH_MID; MMQ(af, bfrH, 1, 1); PH_END;

        // ---- P8: buf1 Q(1,0) | stage B1(U+3)->buf1 | publish buf0 ----
        if (pf) {
            STG(1, 3, srcB0 + H + k0 + 192);
            if constexpr (ASRC == 1)
                asm volatile("s_waitcnt vmcnt(12)" ::: "memory");
            else
                asm volatile("s_waitcnt vmcnt(4)" ::: "memory");
        } else {
            asm volatile("s_waitcnt vmcnt(0)" ::: "memory");
        }
        PH_MID; MMQ(af, bfrL, 1, 0); PH_END;
    }

    // ---- epilogue: BN + LeakyReLU (+ xq for MODE 1), write-combined -------
    const int bq = row0 >> 11;  // batch index (tile rows within one batch)
    float scl[4], tcn[4], xqv[4];
#pragma unroll
    for (int j = 0; j < 4; ++j) {
        const int c = col0 + wn * 64 + j * 16 + lr;
        scl[j] = Gg[c] * rsqrtf(Gv[c] + 1e-5f);
        tcn[j] = Gb[c] - Gm[c] * scl[j];
        xqv[j] = (MODE == 1) ? xq[bq * 2048 + c] : 0.f;
    }
#pragma unroll
    for (int i = 0; i < 8; ++i) {
#pragma unroll
        for (int rI = 0; rI < 4; ++rI) {
            const int r = row0 + wm * 128 + i * 16 + kg * 4 + rI;
            const size_t rowoff = (size_t)r * N + col0 + wn * 64 + lr;
#pragma unroll
            for (int j = 0; j < 4; ++j) {
                float val = acc[i][j][rI] * scl[j] + tcn[j];
                val = LRELU(val) + xqv[j];
                out[rowoff + j * 16] = __float2bfloat16(val);
            }
        }
    }
}

// ------ GEMM3 (M x 64, K=512) + layer-4 + bn4, LDS-staged (R14-proven) -----
__global__ __launch_bounds__(256, 2)
void gemm3_l4(const __hip_bfloat16* __restrict__ A,    // s2b [M,512]
              const __hip_bfloat16* __restrict__ W3b,  // [64,512]
              const float* __restrict__ W4,            // [64]
              const float* __restrict__ g3, const float* __restrict__ b3,
              const float* __restrict__ m3, const float* __restrict__ v3,
              const float* __restrict__ g4, const float* __restrict__ b4,
              const float* __restrict__ m4, const float* __restrict__ v4,
              float* __restrict__ logits) {
    __shared__ __hip_bfloat16 lA[128 * 32];     // 8 KB
    __shared__ __hip_bfloat16 lB[64 * 520];     // 66.6 KB (padded rows)
    const int tid = threadIdx.x;
    const int lane = tid & 63;
    const int wv = tid >> 6;
    const int row0 = blockIdx.x * 128;
    const int lr = lane & 15, kg = lane >> 4;

    // stage W3b once (coalesced read, padded LDS write)
#pragma unroll
    for (int p = 0; p < 16; ++p) {
        const int idx = tid * 8 + p * 2048;
        const int r = idx >> 9, c = idx & 511;
        bf16x8 v = *reinterpret_cast<const bf16x8*>(W3b + idx);
        *reinterpret_cast<bf16x8*>(&lB[r * 520 + c]) = v;
    }

    // A staging: lane covers row wv*32+(lane>>2), chunk lane&3; source chunk
    // pre-swizzled by (row>>1)&3 = (lane>>3)&3.
    const int schunk = (lane & 3) ^ ((lane >> 3) & 3);
    const __hip_bfloat16* Ag = A + (size_t)(row0 + wv * 32 + (lane >> 2)) * 512 + schunk * 8;
    __hip_bfloat16* lAp = lA + wv * 1024;

    // ds_read offsets: rows wv*32 + i*16 + lr -> key (lr>>1)&3
    const int koff = ((kg ^ ((lr >> 1) & 3)) << 3);
    const int aoff = (wv * 32 + lr) * 32 + koff;

    f32x4 acc[2][4];
#pragma unroll
    for (int i = 0; i < 2; ++i)
#pragma unroll
        for (int j = 0; j < 4; ++j) acc[i][j] = (f32x4){0.f, 0.f, 0.f, 0.f};

    for (int k = 0; k < 512; k += 32) {
        gload16(lAp,       Ag + k);
        gload16(lAp + 512, Ag + k + (size_t)16 * 512);
        __syncthreads();   // drains vmcnt (A DMA) + lgkm (B writes, 1st iter)

        bf16x8 a[2], b[4];
#pragma unroll
        for (int i = 0; i < 2; ++i)
            a[i] = *reinterpret_cast<const bf16x8*>(lA + aoff + i * 512);
#pragma unroll
        for (int j = 0; j < 4; ++j)
            b[j] = *reinterpret_cast<const bf16x8*>(&lB[(j * 16 + lr) * 520 + k + kg * 8]);
#pragma unroll
        for (int i = 0; i < 2; ++i)
#pragma unroll
            for (int j = 0; j < 4; ++j)
                acc[i][j] = __builtin_amdgcn_mfma_f32_16x16x32_bf16(a[i], b[j], acc[i][j], 0, 0, 0);
        __syncthreads();   // reads consumed before next stage overwrites
    }

    const float sc4 = g4[0] * rsqrtf(v4[0] + 1e-5f);
    const float tc4 = b4[0] - m4[0] * sc4;
#pragma unroll
    for (int i = 0; i < 2; ++i) {
        float t[4] = {0.f, 0.f, 0.f, 0.f};
#pragma unroll
        for (int j = 0; j < 4; ++j) {
            const int c = j * 16 + lr;
            const float sc = g3[c] * rsqrtf(v3[c] + 1e-5f);
            const float tc = b3[c] - m3[c] * sc;
            const float w4c = W4[c];
#pragma unroll
            for (int rI = 0; rI < 4; ++rI) {
                float v = acc[i][j][rI] * sc + tc;
                t[rI] += LRELU(v) * w4c;
            }
        }
#pragma unroll
        for (int m = 1; m < 16; m <<= 1)
#pragma unroll
            for (int rI = 0; rI < 4; ++rI) t[rI] += __shfl_xor(t[rI], m, 64);
        if (lr == 0) {
#pragma unroll
            for (int rI = 0; rI < 4; ++rI) {
                float lg = t[rI] * sc4 + tc4;
                logits[row0 + wv * 32 + i * 16 + kg * 4 + rI] = LRELU(lg);
            }
        }
    }
}

// ---------------- softmax over N=2048 per batch ----------------------------
__global__ void softmax2048(const float* __restrict__ logits, float* __restrict__ scores) {
    __shared__ float sh[2048];
    __shared__ float red[256];
    const int b = blockIdx.x, tid = threadIdx.x;
    float lmax = -1e30f;
#pragma unroll
    for (int it = 0; it < 8; ++it) {
        const int n = tid + it * 256;
        float v = logits[b * 2048 + n];
        sh[n] = v;
        lmax = fmaxf(lmax, v);
    }
    red[tid] = lmax;
    __syncthreads();
    for (int s = 128; s > 0; s >>= 1) {
        if (tid < s) red[tid] = fmaxf(red[tid], red[tid + s]);
        __syncthreads();
    }
    const float gmax = red[0];
    __syncthreads();
    float lsum = 0.f;
#pragma unroll
    for (int it = 0; it < 8; ++it) {
        const int n = tid + it * 256;
        float e = expf(sh[n] - gmax);
        sh[n] = e;
        lsum += e;
    }
    red[tid] = lsum;
    __syncthreads();
    for (int s = 128; s > 0; s >>= 1) {
        if (tid < s) red[tid] += red[tid + s];
        __syncthreads();
    }
    const float inv = 1.f / red[0];
#pragma unroll
    for (int it = 0; it < 8; ++it) {
        const int n = tid + it * 256;
        scores[b * 2048 + n] = sh[n] * inv;
    }
}

// ---------------- pooling over features, then subtract xq ------------------
// out[b,e] = sum_n features[b,n,e]*scores[b,n] - xq[b,e]   (sum scores = 1)
__global__ void pool_partial(const __hip_bfloat16* __restrict__ feats,
                             const float* __restrict__ scores,
                             float* __restrict__ partial) {
    const int b = blockIdx.y, nc = blockIdx.x;  // 32 chunks of 64 rows
    const int e0 = threadIdx.x * 8;
    float acc[8] = {0, 0, 0, 0, 0, 0, 0, 0};
    const size_t base = ((size_t)b * 2048 + nc * 64) * 2048;
    for (int i = 0; i < 64; ++i) {
        const float sc = scores[b * 2048 + nc * 64 + i];
        bf16x8 v = *reinterpret_cast<const bf16x8*>(feats + base + (size_t)i * 2048 + e0);
#pragma unroll
        for (int j = 0; j < 8; ++j) acc[j] += sc * (float)v[j];
    }
    float* p = partial + ((size_t)(b * 32 + nc)) * 2048 + e0;
#pragma unroll
    for (int j = 0; j < 8; ++j) p[j] = acc[j];
}

__global__ void pool_reduce(const float* __restrict__ partial,
                            const float* __restrict__ xq,
                            float* __restrict__ out) {
    const int i = blockIdx.x * blockDim.x + threadIdx.x;  // 0..32767
    const int b = i >> 11, e = i & 2047;
    float s = 0.f;
#pragma unroll
    for (int nc = 0; nc < 32; ++nc) s += partial[((size_t)(b * 32 + nc)) * 2048 + e];
    out[i] = s - xq[i];
}

// ---------------------------------------------------------------------------
extern "C" void kernel_launch(void* const* d_in, const int* in_sizes, int n_in,
                              void* d_out, int out_size, void* d_ws, size_t ws_size,
                              hipStream_t stream) {
    const float* xq = (const float*)d_in[0];
    const float* xk = (const float*)d_in[1];
    const float* W1 = (const float*)d_in[2];
    const float* W2 = (const float*)d_in[3];
    const float* W3 = (const float*)d_in[4];
    const float* W4 = (const float*)d_in[5];
    const float* g1 = (const float*)d_in[6], *b1 = (const float*)d_in[7];
    const float* m1 = (const float*)d_in[8], *v1 = (const float*)d_in[9];
    const float* g2 = (const float*)d_in[10], *b2 = (const float*)d_in[11];
    const float* m2 = (const float*)d_in[12], *v2 = (const float*)d_in[13];
    const float* g3 = (const float*)d_in[14], *b3 = (const float*)d_in[15];
    const float* m3 = (const float*)d_in[16], *v3 = (const float*)d_in[17];
    const float* g4 = (const float*)d_in[18], *b4 = (const float*)d_in[19];
    const float* m4 = (const float*)d_in[20], *v4 = (const float*)d_in[21];

    const int M = 32768;  // B*N = 16*2048

    char* ws = (char*)d_ws;
    size_t off = 0;
    auto alloc = [&](size_t bytes) {
        void* p = ws + off;
        off += (bytes + 255) & ~(size_t)255;
        return p;
    };
    __hip_bfloat16* w1b   = (__hip_bfloat16*)alloc((size_t)2048 * 512 * 2);
    __hip_bfloat16* w2b   = (__hip_bfloat16*)alloc((size_t)512 * 2048 * 2);
    __hip_bfloat16* w3b   = (__hip_bfloat16*)alloc((size_t)64 * 512 * 2);
    __hip_bfloat16* featb = (__hip_bfloat16*)alloc((size_t)M * 2048 * 2);
    __hip_bfloat16* s2b   = (__hip_bfloat16*)alloc((size_t)M * 512 * 2);
    float* logits         = (float*)alloc((size_t)M * 4);
    float* scores         = (float*)alloc((size_t)16 * 2048 * 4);
    float* partial        = (float*)alloc((size_t)16 * 32 * 2048 * 4);

    // convert weights only (xk consumed as f32 by GEMM1's T14 A-path)
    cvt_w<<<512, 256, 0, stream>>>(
        W1, w1b, 2048 * 512 / 4,
        W2, w2b, 512 * 2048 / 4,
        W3, w3b, 64 * 512 / 4);

    // GEMM1: features = lrelu(bn1(xk @ W1^T)) + xq   [M,2048] bf16
    gemm8p<2048, 512, 1, 1><<<1024, 512, 0, stream>>>(
        nullptr, xk, w1b, xq, featb, g1, b1, m1, v1);

    // GEMM2: s2 = lrelu(bn2(features @ W2^T))        [M,512] bf16
    gemm8p<512, 2048, 2, 0><<<256, 512, 0, stream>>>(
        featb, nullptr, w2b, nullptr, s2b, g2, b2, m2, v2);

    // GEMM3 + layer4: logits [M] f32
    gemm3_l4<<<256, 256, 0, stream>>>(s2b, w3b, W4,
                                      g3, b3, m3, v3, g4, b4, m4, v4, logits);

    // softmax over N per batch
    softmax2048<<<16, 256, 0, stream>>>(logits, scores);

    // pooling (+ subtract xq)
    pool_partial<<<dim3(32, 16), 256, 0, stream>>>(featb, scores, partial);
    pool_reduce<<<128, 256, 0, stream>>>(partial, xq, (float*)d_out);
}

// Round 16
// 204.614 us; speedup vs baseline: 1.4700x; 1.4700x over previous
//
#include <hip/hip_runtime.h>
#include <hip/hip_bf16.h>

typedef __bf16 bf16x8 __attribute__((ext_vector_type(8)));
typedef float f32x4 __attribute__((ext_vector_type(4)));
typedef __attribute__((address_space(3))) void lds_void_t;
typedef __attribute__((address_space(1))) void gbl_void_t;

#define LRELU(x) ((x) >= 0.f ? (x) : 0.2f * (x))

__device__ __forceinline__ void gload16(void* lds_uniform, const void* gsrc) {
    __builtin_amdgcn_global_load_lds((const gbl_void_t*)gsrc, (lds_void_t*)lds_uniform,
                                     16, 0, 0);
}

__device__ __forceinline__ unsigned short f2u(float f) {
    __hip_bfloat16 h = __float2bfloat16(f);
    return reinterpret_cast<unsigned short&>(h);
}

// ---------------- fused f32 -> bf16 convert (4 tensors, one launch) --------
__global__ void cvt_fused(const float* __restrict__ a, __hip_bfloat16* __restrict__ oa, int na,
                          const float* __restrict__ b, __hip_bfloat16* __restrict__ ob, int nb,
                          const float* __restrict__ c, __hip_bfloat16* __restrict__ oc, int nc,
                          const float* __restrict__ d, __hip_bfloat16* __restrict__ od, int nd) {
    const int stride = gridDim.x * blockDim.x;
    const int total = na + nb + nc + nd;
    for (int i = blockIdx.x * blockDim.x + threadIdx.x; i < total; i += stride) {
        const float* s; __hip_bfloat16* o; int j = i;
        if (j < na) { s = a; o = oa; }
        else {
            j -= na;
            if (j < nb) { s = b; o = ob; }
            else {
                j -= nb;
                if (j < nc) { s = c; o = oc; }
                else { j -= nc; s = d; o = od; }
            }
        }
        float4 v = reinterpret_cast<const float4*>(s)[j];
        ushort4 u;
        u.x = f2u(v.x); u.y = f2u(v.y); u.z = f2u(v.z); u.w = f2u(v.w);
        reinterpret_cast<ushort4*>(o)[j] = u;
    }
}

// ======================= 256x256 8-phase GEMM (R8 config, best) ============
// 8 waves (2M x 4N), per-wave C = 128x64 (acc[8][4] f32x4). BK=64, 2 K-tiles
// per iteration. LDS = 2 bufs x 4 regions (A0,A1,B0,B1) x 8192 elems = 128KB.
// Chunk-XOR swizzle: chunk c of row r at position c^(r&7); linear gload_lds
// dest + pre-swizzled global source; same XOR on ds_read.
// Ledger: RAW via vmcnt(4)+barrier publishes at P4/P8 (only the 4 newest
// loads in flight => prior buffer landed, block-wide after barrier); WAR via
// region-age >= 1 phase barrier since last ds_read (drained by PH_MID lgkm0);
// WAW ancient; last iter vmcnt(0).
// MODE 1: out = bf16(lrelu(bn(A@B^T)) + xq) ; MODE 2: out = bf16(lrelu(bn))
// ===========================================================================

#define MMQ(AF, BF, IH, JH)                                                   \
    {                                                                         \
        _Pragma("unroll") for (int r = 0; r < 4; ++r) {                       \
            _Pragma("unroll") for (int c = 0; c < 2; ++c) {                   \
                _Pragma("unroll") for (int s = 0; s < 2; ++s) {               \
                    acc[(IH) * 4 + r][(JH) * 2 + c] =                         \
                        __builtin_amdgcn_mfma_f32_16x16x32_bf16(              \
                            AF[r][s], BF[c][s],                               \
                            acc[(IH) * 4 + r][(JH) * 2 + c], 0, 0, 0);        \
                }                                                             \
            }                                                                 \
        }                                                                     \
    }

#define LDA_(AF, BUF, IH)                                                     \
    {                                                                         \
        const __hip_bfloat16* _ab = sm + (BUF) * 32768 + wm * 8192;           \
        _Pragma("unroll") for (int r = 0; r < 4; ++r) {                       \
            const int _row = (IH) * 64 + r * 16 + lr;                         \
            _Pragma("unroll") for (int s = 0; s < 2; ++s) {                   \
                AF[r][s] = *reinterpret_cast<const bf16x8*>(                  \
                    _ab + _row * 64 + (((s * 4 + kg) ^ (lr & 7)) * 8));       \
            }                                                                 \
        }                                                                     \
    }

#define LDB_(BF, BUF, JH)                                                     \
    {                                                                         \
        const __hip_bfloat16* _bb =                                           \
            sm + (BUF) * 32768 + (2 + (wn >> 1)) * 8192;                      \
        _Pragma("unroll") for (int c = 0; c < 2; ++c) {                       \
            const int _row = (wn & 1) * 64 + ((JH) * 2 + c) * 16 + lr;        \
            _Pragma("unroll") for (int s = 0; s < 2; ++s) {                   \
                BF[c][s] = *reinterpret_cast<const bf16x8*>(                  \
                    _bb + _row * 64 + (((s * 4 + kg) ^ (lr & 7)) * 8));       \
            }                                                                 \
        }                                                                     \
    }

#define PH_MID                                                                \
    __builtin_amdgcn_s_barrier();                                             \
    asm volatile("s_waitcnt lgkmcnt(0)" ::: "memory");                        \
    __builtin_amdgcn_sched_barrier(0);                                        \
    __builtin_amdgcn_s_setprio(1);

#define PH_END                                                                \
    __builtin_amdgcn_s_setprio(0);                                            \
    __builtin_amdgcn_sched_barrier(0);                                        \
    __builtin_amdgcn_s_barrier();

template <int N, int K, int MODE>
__global__ __launch_bounds__(512, 1)
void gemm8p(const __hip_bfloat16* __restrict__ A,
            const __hip_bfloat16* __restrict__ Bw,
            const float* __restrict__ xq,
            __hip_bfloat16* __restrict__ out,
            const float* __restrict__ Gg, const float* __restrict__ Gb,
            const float* __restrict__ Gm, const float* __restrict__ Gv) {
    __shared__ __hip_bfloat16 sm[65536];   // 128 KB

    // XCD-aware block swizzle (nwg % 8 == 0 by launch config)
    const int nwg = gridDim.x;
    const int cpx = nwg >> 3;
    const int bid = blockIdx.x;
    const int orig = (bid & 7) * cpx + (bid >> 3);
    constexpr int NCB = N / 256;
    const int row0 = (orig / NCB) * 256;
    const int col0 = (orig % NCB) * 256;

    const int tid = threadIdx.x;
    const int lane = tid & 63;
    const int wv = tid >> 6;          // 0..7
    const int wm = wv >> 2, wn = wv & 3;
    const int lr = lane & 15, kg = lane >> 4;

    // staging source: thread tid covers (row_local = g*64 + tid/8,
    // chunk_pos = tid&7) of a half-tile; source chunk = pos ^ (row&7).
    const int schunk = (tid & 7) ^ ((tid >> 3) & 7);
    const __hip_bfloat16* srcA0 = A + (size_t)(row0 + (tid >> 3)) * K + schunk * 8;
    const __hip_bfloat16* srcB0 = Bw + (size_t)(col0 + (tid >> 3)) * K + schunk * 8;
    constexpr size_t H = (size_t)128 * K;   // +128 rows (second half-tile)

    auto STG = [&](int buf, int region, const __hip_bfloat16* src) {
        __hip_bfloat16* l = sm + buf * 32768 + region * 8192 + wv * 512;
        gload16(l, src);
        gload16(l + 4096, src + (size_t)64 * K);   // g=1: rows +64
    };

    f32x4 acc[8][4];
#pragma unroll
    for (int i = 0; i < 8; ++i)
#pragma unroll
        for (int j = 0; j < 4; ++j) acc[i][j] = (f32x4){0.f, 0.f, 0.f, 0.f};

    bf16x8 af[4][2], bfrL[2][2], bfrH[2][2];

    // ---- prologue: buf0 = tile0 (all 4 regions), buf1 = tile1 (B only) ----
    STG(0, 0, srcA0);          // A0(T0)
    STG(0, 1, srcA0 + H);      // A1(T0)
    STG(0, 2, srcB0);          // B0(T0)
    STG(0, 3, srcB0 + H);      // B1(T0)
    STG(1, 2, srcB0 + 64);     // B0(T1)
    STG(1, 3, srcB0 + H + 64); // B1(T1)
    asm volatile("s_waitcnt vmcnt(4)" ::: "memory");   // buf0 landed
    __builtin_amdgcn_s_barrier();

    constexpr int niter = K / 128;
    for (int it = 0; it < niter; ++it) {
        const int k0 = it * 128;           // tile U k-offset
        const bool pf = (it + 1 < niter);

        // ---- P1: buf0 Q(0,0) | stage A0(U+1)->buf1 ----
        LDA_(af, 0, 0);
        LDB_(bfrL, 0, 0);
        STG(1, 0, srcA0 + k0 + 64);
        PH_MID; MMQ(af, bfrL, 0, 0); PH_END;

        // ---- P2: buf0 Q(0,1) | stage A1(U+1)->buf1 ----
        LDB_(bfrH, 0, 1);
        STG(1, 1, srcA0 + H + k0 + 64);
        PH_MID; MMQ(af, bfrH, 0, 1); PH_END;

        // ---- P3: buf0 Q(1,1) | stage B0(U+2)->buf0 ----
        LDA_(af, 0, 1);
        if (pf) STG(0, 2, srcB0 + k0 + 128);
        PH_MID; MMQ(af, bfrH, 1, 1); PH_END;

        // ---- P4: buf0 Q(1,0) | stage B1(U+2)->buf0 | vmcnt ----
        if (pf) {
            STG(0, 3, srcB0 + H + k0 + 128);
            asm volatile("s_waitcnt vmcnt(4)" ::: "memory");  // buf1 landed
        } else {
            asm volatile("s_waitcnt vmcnt(0)" ::: "memory");
        }
        PH_MID; MMQ(af, bfrL, 1, 0); PH_END;

        // ---- P5: buf1 Q(0,0) | stage A0(U+2)->buf0 ----
        LDA_(af, 1, 0);
        LDB_(bfrL, 1, 0);
        if (pf) STG(0, 0, srcA0 + k0 + 128);
        PH_MID; MMQ(af, bfrL, 0, 0); PH_END;

        // ---- P6: buf1 Q(0,1) | stage A1(U+2)->buf0 ----
        LDB_(bfrH, 1, 1);
        if (pf) STG(0, 1, srcA0 + H + k0 + 128);
        PH_MID; MMQ(af, bfrH, 0, 1); PH_END;

        // ---- P7: buf1 Q(1,1) | stage B0(U+3)->buf1 ----
        LDA_(af, 1, 1);
        if (pf) STG(1, 2, srcB0 + k0 + 192);
        PH_MID; MMQ(af, bfrH, 1, 1); PH_END;

        // ---- P8: buf1 Q(1,0) | stage B1(U+3)->buf1 | vmcnt ----
        if (pf) {
            STG(1, 3, srcB0 + H + k0 + 192);
            asm volatile("s_waitcnt vmcnt(4)" ::: "memory");  // buf0(U+2) landed
        } else {
            asm volatile("s_waitcnt vmcnt(0)" ::: "memory");
        }
        PH_MID; MMQ(af, bfrL, 1, 0); PH_END;
    }

    // ---- epilogue: BN + LeakyReLU (+ xq for MODE 1), write-combined -------
    const int bq = row0 >> 11;  // batch index (tile rows within one batch)
    float scl[4], tcn[4], xqv[4];
#pragma unroll
    for (int j = 0; j < 4; ++j) {
        const int c = col0 + wn * 64 + j * 16 + lr;
        scl[j] = Gg[c] * rsqrtf(Gv[c] + 1e-5f);
        tcn[j] = Gb[c] - Gm[c] * scl[j];
        xqv[j] = (MODE == 1) ? xq[bq * 2048 + c] : 0.f;
    }
#pragma unroll
    for (int i = 0; i < 8; ++i) {
#pragma unroll
        for (int rI = 0; rI < 4; ++rI) {
            const int r = row0 + wm * 128 + i * 16 + kg * 4 + rI;
            const size_t rowoff = (size_t)r * N + col0 + wn * 64 + lr;
#pragma unroll
            for (int j = 0; j < 4; ++j) {
                float val = acc[i][j][rI] * scl[j] + tcn[j];
                val = LRELU(val) + xqv[j];
                out[rowoff + j * 16] = __float2bfloat16(val);
            }
        }
    }
}

// ------ GEMM3 (M x 64, K=512) + layer-4 + bn4, LDS-staged (R14-proven) -----
// A tile [128][32] staged per K-step via gload16 + 2-way chunk-XOR swizzle
// (0-conflict); W3 staged ONCE into padded LDS [64][520]. 2 blocks/CU.
__global__ __launch_bounds__(256, 2)
void gemm3_l4(const __hip_bfloat16* __restrict__ A,    // s2b [M,512]
              const __hip_bfloat16* __restrict__ W3b,  // [64,512]
              const float* __restrict__ W4,            // [64]
              const float* __restrict__ g3, const float* __restrict__ b3,
              const float* __restrict__ m3, const float* __restrict__ v3,
              const float* __restrict__ g4, const float* __restrict__ b4,
              const float* __restrict__ m4, const float* __restrict__ v4,
              float* __restrict__ logits) {
    __shared__ __hip_bfloat16 lA[128 * 32];     // 8 KB
    __shared__ __hip_bfloat16 lB[64 * 520];     // 66.6 KB (padded rows)
    const int tid = threadIdx.x;
    const int lane = tid & 63;
    const int wv = tid >> 6;
    const int row0 = blockIdx.x * 128;
    const int lr = lane & 15, kg = lane >> 4;

    // stage W3b once (coalesced read, padded LDS write)
#pragma unroll
    for (int p = 0; p < 16; ++p) {
        const int idx = tid * 8 + p * 2048;
        const int r = idx >> 9, c = idx & 511;
        bf16x8 v = *reinterpret_cast<const bf16x8*>(W3b + idx);
        *reinterpret_cast<bf16x8*>(&lB[r * 520 + c]) = v;
    }

    // A staging: lane covers row wv*32+(lane>>2), chunk lane&3; source chunk
    // pre-swizzled by (row>>1)&3 = (lane>>3)&3.
    const int schunk = (lane & 3) ^ ((lane >> 3) & 3);
    const __hip_bfloat16* Ag = A + (size_t)(row0 + wv * 32 + (lane >> 2)) * 512 + schunk * 8;
    __hip_bfloat16* lAp = lA + wv * 1024;

    // ds_read offsets: rows wv*32 + i*16 + lr -> key (lr>>1)&3
    const int koff = ((kg ^ ((lr >> 1) & 3)) << 3);
    const int aoff = (wv * 32 + lr) * 32 + koff;

    f32x4 acc[2][4];
#pragma unroll
    for (int i = 0; i < 2; ++i)
#pragma unroll
        for (int j = 0; j < 4; ++j) acc[i][j] = (f32x4){0.f, 0.f, 0.f, 0.f};

    for (int k = 0; k < 512; k += 32) {
        gload16(lAp,       Ag + k);
        gload16(lAp + 512, Ag + k + (size_t)16 * 512);
        __syncthreads();   // drains vmcnt (A DMA) + lgkm (B writes, 1st iter)

        bf16x8 a[2], b[4];
#pragma unroll
        for (int i = 0; i < 2; ++i)
            a[i] = *reinterpret_cast<const bf16x8*>(lA + aoff + i * 512);
#pragma unroll
        for (int j = 0; j < 4; ++j)
            b[j] = *reinterpret_cast<const bf16x8*>(&lB[(j * 16 + lr) * 520 + k + kg * 8]);
#pragma unroll
        for (int i = 0; i < 2; ++i)
#pragma unroll
            for (int j = 0; j < 4; ++j)
                acc[i][j] = __builtin_amdgcn_mfma_f32_16x16x32_bf16(a[i], b[j], acc[i][j], 0, 0, 0);
        __syncthreads();   // reads consumed before next stage overwrites
    }

    const float sc4 = g4[0] * rsqrtf(v4[0] + 1e-5f);
    const float tc4 = b4[0] - m4[0] * sc4;
#pragma unroll
    for (int i = 0; i < 2; ++i) {
        float t[4] = {0.f, 0.f, 0.f, 0.f};
#pragma unroll
        for (int j = 0; j < 4; ++j) {
            const int c = j * 16 + lr;
            const float sc = g3[c] * rsqrtf(v3[c] + 1e-5f);
            const float tc = b3[c] - m3[c] * sc;
            const float w4c = W4[c];
#pragma unroll
            for (int rI = 0; rI < 4; ++rI) {
                float v = acc[i][j][rI] * sc + tc;
                t[rI] += LRELU(v) * w4c;
            }
        }
#pragma unroll
        for (int m = 1; m < 16; m <<= 1)
#pragma unroll
            for (int rI = 0; rI < 4; ++rI) t[rI] += __shfl_xor(t[rI], m, 64);
        if (lr == 0) {
#pragma unroll
            for (int rI = 0; rI < 4; ++rI) {
                float lg = t[rI] * sc4 + tc4;
                logits[row0 + wv * 32 + i * 16 + kg * 4 + rI] = LRELU(lg);
            }
        }
    }
}

// ---------------- softmax over N=2048 per batch ----------------------------
__global__ void softmax2048(const float* __restrict__ logits, float* __restrict__ scores) {
    __shared__ float sh[2048];
    __shared__ float red[256];
    const int b = blockIdx.x, tid = threadIdx.x;
    float lmax = -1e30f;
#pragma unroll
    for (int it = 0; it < 8; ++it) {
        const int n = tid + it * 256;
        float v = logits[b * 2048 + n];
        sh[n] = v;
        lmax = fmaxf(lmax, v);
    }
    red[tid] = lmax;
    __syncthreads();
    for (int s = 128; s > 0; s >>= 1) {
        if (tid < s) red[tid] = fmaxf(red[tid], red[tid + s]);
        __syncthreads();
    }
    const float gmax = red[0];
    __syncthreads();
    float lsum = 0.f;
#pragma unroll
    for (int it = 0; it < 8; ++it) {
        const int n = tid + it * 256;
        float e = expf(sh[n] - gmax);
        sh[n] = e;
        lsum += e;
    }
    red[tid] = lsum;
    __syncthreads();
    for (int s = 128; s > 0; s >>= 1) {
        if (tid < s) red[tid] += red[tid + s];
        __syncthreads();
    }
    const float inv = 1.f / red[0];
#pragma unroll
    for (int it = 0; it < 8; ++it) {
        const int n = tid + it * 256;
        scores[b * 2048 + n] = sh[n] * inv;
    }
}

// ---------------- pooling over features, then subtract xq ------------------
// out[b,e] = sum_n features[b,n,e]*scores[b,n] - xq[b,e]   (sum scores = 1)
__global__ void pool_partial(const __hip_bfloat16* __restrict__ feats,
                             const float* __restrict__ scores,
                             float* __restrict__ partial) {
    const int b = blockIdx.y, nc = blockIdx.x;  // 32 chunks of 64 rows
    const int e0 = threadIdx.x * 8;
    float acc[8] = {0, 0, 0, 0, 0, 0, 0, 0};
    const size_t base = ((size_t)b * 2048 + nc * 64) * 2048;
    for (int i = 0; i < 64; ++i) {
        const float sc = scores[b * 2048 + nc * 64 + i];
        bf16x8 v = *reinterpret_cast<const bf16x8*>(feats + base + (size_t)i * 2048 + e0);
#pragma unroll
        for (int j = 0; j < 8; ++j) acc[j] += sc * (float)v[j];
    }
    float* p = partial + ((size_t)(b * 32 + nc)) * 2048 + e0;
#pragma unroll
    for (int j = 0; j < 8; ++j) p[j] = acc[j];
}

__global__ void pool_reduce(const float* __restrict__ partial,
                            const float* __restrict__ xq,
                            float* __restrict__ out) {
    const int i = blockIdx.x * blockDim.x + threadIdx.x;  // 0..32767
    const int b = i >> 11, e = i & 2047;
    float s = 0.f;
#pragma unroll
    for (int nc = 0; nc < 32; ++nc) s += partial[((size_t)(b * 32 + nc)) * 2048 + e];
    out[i] = s - xq[i];
}

// ---------------------------------------------------------------------------
extern "C" void kernel_launch(void* const* d_in, const int* in_sizes, int n_in,
                              void* d_out, int out_size, void* d_ws, size_t ws_size,
                              hipStream_t stream) {
    const float* xq = (const float*)d_in[0];
    const float* xk = (const float*)d_in[1];
    const float* W1 = (const float*)d_in[2];
    const float* W2 = (const float*)d_in[3];
    const float* W3 = (const float*)d_in[4];
    const float* W4 = (const float*)d_in[5];
    const float* g1 = (const float*)d_in[6], *b1 = (const float*)d_in[7];
    const float* m1 = (const float*)d_in[8], *v1 = (const float*)d_in[9];
    const float* g2 = (const float*)d_in[10], *b2 = (const float*)d_in[11];
    const float* m2 = (const float*)d_in[12], *v2 = (const float*)d_in[13];
    const float* g3 = (const float*)d_in[14], *b3 = (const float*)d_in[15];
    const float* m3 = (const float*)d_in[16], *v3 = (const float*)d_in[17];
    const float* g4 = (const float*)d_in[18], *b4 = (const float*)d_in[19];
    const float* m4 = (const float*)d_in[20], *v4 = (const float*)d_in[21];

    const int M = 32768;  // B*N = 16*2048

    char* ws = (char*)d_ws;
    size_t off = 0;
    auto alloc = [&](size_t bytes) {
        void* p = ws + off;
        off += (bytes + 255) & ~(size_t)255;
        return p;
    };
    __hip_bfloat16* xkb   = (__hip_bfloat16*)alloc((size_t)M * 512 * 2);
    __hip_bfloat16* w1b   = (__hip_bfloat16*)alloc((size_t)2048 * 512 * 2);
    __hip_bfloat16* w2b   = (__hip_bfloat16*)alloc((size_t)512 * 2048 * 2);
    __hip_bfloat16* w3b   = (__hip_bfloat16*)alloc((size_t)64 * 512 * 2);
    __hip_bfloat16* featb = (__hip_bfloat16*)alloc((size_t)M * 2048 * 2);
    __hip_bfloat16* s2b   = (__hip_bfloat16*)alloc((size_t)M * 512 * 2);
    float* logits         = (float*)alloc((size_t)M * 4);
    float* scores         = (float*)alloc((size_t)16 * 2048 * 4);
    float* partial        = (float*)alloc((size_t)16 * 32 * 2048 * 4);

    // fused converts (one launch)
    cvt_fused<<<4096, 256, 0, stream>>>(
        xk, xkb, M * 512 / 4,
        W1, w1b, 2048 * 512 / 4,
        W2, w2b, 512 * 2048 / 4,
        W3, w3b, 64 * 512 / 4);

    // GEMM1: features = lrelu(bn1(xk @ W1^T)) + xq   [M,2048] bf16
    gemm8p<2048, 512, 1><<<1024, 512, 0, stream>>>(
        xkb, w1b, xq, featb, g1, b1, m1, v1);

    // GEMM2: s2 = lrelu(bn2(features @ W2^T))        [M,512] bf16
    gemm8p<512, 2048, 2><<<256, 512, 0, stream>>>(
        featb, w2b, nullptr, s2b, g2, b2, m2, v2);

    // GEMM3 + layer4: logits [M] f32
    gemm3_l4<<<256, 256, 0, stream>>>(s2b, w3b, W4,
                                      g3, b3, m3, v3, g4, b4, m4, v4, logits);

    // softmax over N per batch
    softmax2048<<<16, 256, 0, stream>>>(logits, scores);

    // pooling (+ subtract xq)
    pool_partial<<<dim3(32, 16), 256, 0, stream>>>(featb, scores, partial);
    pool_reduce<<<128, 256, 0, stream>>>(partial, xq, (float*)d_out);
}